// Round 8
// baseline (189.076 us; speedup 1.0000x reference)
//
#include <hip/hip_runtime.h>
#include <hip/hip_bf16.h>

#define NN 50000
#define EE 800000
#define FF 128
#define HH 128
#define HID2 64
#define TT 8
#define GG 64
#define NB 196          // buckets of 256 dst nodes (NN < 196*256; NN < 2^16)
#define NSB 256         // scatter blocks
#define EPB (EE / NSB)  // 3125 edges per scatter block
#define NPAD 50048      // NN padded to 64 (782 * 64)
#define GEMMB (NPAD / 64)  // 782 gemm tiles

using frag_ab = __attribute__((ext_vector_type(8))) short;  // 8 bf16
using frag_cd = __attribute__((ext_vector_type(4))) float;  // 4 fp32

__device__ inline unsigned short f2bf(float f) {
    union { float f; unsigned u; } v; v.f = f;
    unsigned r = v.u + 0x7fff + ((v.u >> 16) & 1);  // RNE
    return (unsigned short)(r >> 16);
}

__device__ inline int lbound(const int* __restrict__ a, int n, int key) {
    int lo = 0, hi = n;
    while (lo < hi) {
        int mid = (lo + hi) >> 1;
        if (a[mid] < key) lo = mid + 1;
        else hi = mid;
    }
    return lo;
}

// ---- K_FRONT: per-block bucket histogram + W->Wt bf16 + gsum zero ---------
__global__ __launch_bounds__(256) void k_front(const int* __restrict__ dst,
                                               const float* __restrict__ W,
                                               int* __restrict__ table,
                                               unsigned short* __restrict__ wt_bf,
                                               float* __restrict__ gsum) {
    __shared__ int cnt[NB];
    int t = threadIdx.x, blk = blockIdx.x;
    if (blk < 64) {
        int gid = blk * 256 + t;          // 16384 total
        int c = gid >> 7, k = gid & 127;
        wt_bf[gid] = f2bf(W[k * 128 + c]);
    }
    if (blk >= 64 && blk < 96) {
        int gid = (blk - 64) * 256 + t;   // 8192 floats
        gsum[gid] = 0.f;
    }
    for (int i = t; i < NB; i += 256) cnt[i] = 0;
    __syncthreads();
    int e0 = blk * EPB;
    for (int e = e0 + t; e < e0 + EPB; e += 256)
        atomicAdd(&cnt[dst[e] >> 8], 1);
    __syncthreads();
    for (int i = t; i < NB; i += 256) table[blk * NB + i] = cnt[i];
}

// ---- K_SG: co-launched [sort: blocks 0..255] ∥ [gemm: blocks 256..1037] ---
__global__ __launch_bounds__(256) void k_sg(const int* __restrict__ src,
                                            const int* __restrict__ dst,
                                            const int* __restrict__ table,
                                            int* __restrict__ bbase,
                                            unsigned* __restrict__ etmp,
                                            const float* __restrict__ x,
                                            const unsigned short* __restrict__ wt_bf,
                                            unsigned short* __restrict__ hs) {
    int t = threadIdx.x, blk = blockIdx.x;
    if (blk < NSB) {
        __shared__ int s[256];
        __shared__ int ofs[NB];
        __shared__ int cur[NB];
        int pr = 0, to = 0;
        if (t < NB) {
#pragma unroll 8
            for (int r = 0; r < 256; r++) {
                int v = table[r * NB + t];
                to += v;
                pr += (r < blk) ? v : 0;
            }
        }
        s[t] = (t < NB) ? to : 0;
        __syncthreads();
        for (int off = 1; off < 256; off <<= 1) {
            int a = s[t];
            int w = (t >= off) ? s[t - off] : 0;
            __syncthreads();
            s[t] = a + w;
            __syncthreads();
        }
        if (t < NB) {
            int bb = s[t] - to;            // exclusive bucket base
            ofs[t] = pr + bb;
            cur[t] = 0;
            if (blk == 0) bbase[t] = bb;
        }
        if (blk == 0 && t == 0) bbase[NB] = EE;
        __syncthreads();
        int e0 = blk * EPB;
        for (int e = e0 + t; e < e0 + EPB; e += 256) {
            int d = dst[e];
            int b = d >> 8;
            int r = atomicAdd(&cur[b], 1);
            etmp[ofs[b] + r] = ((unsigned)d << 16) | (unsigned)src[e];
        }
    } else {
        // ---- gemm tile (raw bf16 output; dinv applied in aggr) ----
        int vb = blk - NSB;               // 0..781
        int w = t >> 6, lane = t & 63;
        int m = lane & 15, quad = lane >> 4;
        int r0 = vb * 64 + w * 16;
        int row = r0 + m;
        frag_cd acc[8];
#pragma unroll
        for (int nt = 0; nt < 8; nt++) acc[nt] = frag_cd{0.f, 0.f, 0.f, 0.f};
#pragma unroll
        for (int k0 = 0; k0 < 128; k0 += 32) {
            unsigned short av[8];
            if (row < NN) {
                const float4* pp = (const float4*)(x + (size_t)row * 128 + k0 + quad * 8);
                float4 a0 = pp[0], a1 = pp[1];
                av[0] = f2bf(a0.x); av[1] = f2bf(a0.y); av[2] = f2bf(a0.z); av[3] = f2bf(a0.w);
                av[4] = f2bf(a1.x); av[5] = f2bf(a1.y); av[6] = f2bf(a1.z); av[7] = f2bf(a1.w);
            } else {
#pragma unroll
                for (int j = 0; j < 8; j++) av[j] = 0;
            }
            frag_ab a = *(const frag_ab*)av;
#pragma unroll
            for (int nt = 0; nt < 8; nt++) {
                frag_ab bfr = *(const frag_ab*)(wt_bf + (size_t)(nt * 16 + m) * 128 + k0 + quad * 8);
                acc[nt] = __builtin_amdgcn_mfma_f32_16x16x32_bf16(a, bfr, acc[nt], 0, 0, 0);
            }
        }
#pragma unroll
        for (int reg = 0; reg < 4; reg++) {
            int gr = r0 + quad * 4 + reg;
            if (gr < NN) {
#pragma unroll
                for (int nt = 0; nt < 8; nt++)
                    hs[(size_t)gr * 128 + nt * 16 + m] = f2bf(acc[nt][reg]);
            }
        }
    }
}

// ---- K_CSR: per-bucket  hist -> scan -> row_ptr/dinv -> CSR fill ----------
__global__ __launch_bounds__(256) void k_csr(const unsigned* __restrict__ etmp,
                                             const int* __restrict__ bbase,
                                             int* __restrict__ row_ptr,
                                             float* __restrict__ dinv,
                                             int* __restrict__ srcs) {
    __shared__ int s[256];
    __shared__ int cur[256];
    int t = threadIdx.x, b = blockIdx.x;
    s[t] = 0;
    __syncthreads();
    int e0 = bbase[b], e1 = bbase[b + 1];
    for (int e = e0 + t; e < e1; e += 256)
        atomicAdd(&s[(etmp[e] >> 16) & 255], 1);
    __syncthreads();
    int v = s[t];
    for (int off = 1; off < 256; off <<= 1) {
        int a = s[t];
        int w = (t >= off) ? s[t - off] : 0;
        __syncthreads();
        s[t] = a + w;
        __syncthreads();
    }
    int excl = s[t] - v + e0;   // e0 == bbase[b] == row_ptr[b*256]
    int node = b * 256 + t;
    if (node < NN) {
        row_ptr[node] = excl;
        dinv[node] = rsqrtf((float)(v + 1));  // +1 self-loop
    }
    if (b == NB - 1 && t == 0) row_ptr[NN] = EE;
    cur[t] = excl;
    __syncthreads();
    for (int e = e0 + t; e < e1; e += 256) {
        unsigned u = etmp[e];
        int slot = atomicAdd(&cur[(u >> 16) & 255], 1);
        srcs[slot] = (int)(u & 0xffffu);
    }
}

// ---------------- K5: gather(+dinv[src] fma) + bias + relu + pool ----------
// r1 shape (16 qwaves, 2 nodes/qwave) with: (a) 16-deep main gather batch —
// avg deg = 16, so most nodes take ONE srcs->gather round trip instead of
// two; (b) merged node-pair prologue (int2/float2 loads, both self rows
// issued together) — one latency exposure instead of two.
#define ACCS(u, ds) \
    a0 = fmaf(ds, __uint_as_float((u).x << 16), a0); \
    a1 = fmaf(ds, __uint_as_float((u).x & 0xffff0000u), a1); \
    a2 = fmaf(ds, __uint_as_float((u).y << 16), a2); \
    a3 = fmaf(ds, __uint_as_float((u).y & 0xffff0000u), a3); \
    a4 = fmaf(ds, __uint_as_float((u).z << 16), a4); \
    a5 = fmaf(ds, __uint_as_float((u).z & 0xffff0000u), a5); \
    a6 = fmaf(ds, __uint_as_float((u).w << 16), a6); \
    a7 = fmaf(ds, __uint_as_float((u).w & 0xffff0000u), a7);

__global__ __launch_bounds__(256) void k_aggr(const uint4* __restrict__ hs4,
                                              const int* __restrict__ row_ptr,
                                              const int* __restrict__ srcs,
                                              const float* __restrict__ dinv,
                                              const float* __restrict__ bias,
                                              const int* __restrict__ batch,
                                              float* __restrict__ gsum) {
    __shared__ float gacc[8 * 128];   // 4 KB: 8 group slots (span>8 -> global)
    int tid = threadIdx.x;
    int qid = tid >> 4, sub = tid & 15;
    int i_base = blockIdx.x * 32;
    int g_first = batch[i_base];
    int last = i_base + 31; if (last >= NN) last = NN - 1;
    int gspan = batch[last] - g_first + 1;
    bool lds_pool = (gspan <= 8);
    int slots = lds_pool ? gspan : 0;
    for (int idx = tid; idx < slots * 128; idx += 256) gacc[idx] = 0.f;
    __syncthreads();

    const float4* b4 = (const float4*)(bias + sub * 8);
    float4 bb0 = b4[0], bb1 = b4[1];

    float racc[8];
#pragma unroll
    for (int j = 0; j < 8; j++) racc[j] = 0.f;
    int cur_lg = -1;

    int i0 = i_base + qid * 2;        // even; NN even => i0<NN implies i0+1<NN
    if (i0 < NN) {
        // merged prologue: one exposure for both nodes
        int2   bt = *(const int2*)(batch + i0);
        int2   ra = *(const int2*)(row_ptr + i0);
        int    rb = row_ptr[i0 + 2];
        float2 dv = *(const float2*)(dinv + i0);
        uint4  su0 = hs4[(size_t)i0 * 16 + sub];
        uint4  su1 = hs4[(size_t)(i0 + 1) * 16 + sub];

        for (int n = 0; n < 2; n++) {
            int lg  = (n ? bt.y : bt.x) - g_first;
            float di = n ? dv.y : dv.x;
            uint4 su = n ? su1 : su0;
            int e   = n ? ra.y : ra.x;
            int e1  = n ? rb   : ra.y;
            if (lg != cur_lg) {
                if (cur_lg >= 0) {
                    float* gp = lds_pool ? &gacc[cur_lg * 128 + sub * 8]
                                         : &gsum[(g_first + cur_lg) * 128 + sub * 8];
#pragma unroll
                    for (int j = 0; j < 8; j++) atomicAdd(&gp[j], racc[j]);
#pragma unroll
                    for (int j = 0; j < 8; j++) racc[j] = 0.f;
                }
                cur_lg = lg;
            }
            // self term: dinv[i] * h_raw[i]
            float a0 = di * __uint_as_float(su.x << 16);
            float a1 = di * __uint_as_float(su.x & 0xffff0000u);
            float a2 = di * __uint_as_float(su.y << 16);
            float a3 = di * __uint_as_float(su.y & 0xffff0000u);
            float a4 = di * __uint_as_float(su.z << 16);
            float a5 = di * __uint_as_float(su.z & 0xffff0000u);
            float a6 = di * __uint_as_float(su.w << 16);
            float a7 = di * __uint_as_float(su.w & 0xffff0000u);
            // 16-deep main batch: one srcs->gather round trip for avg row
            for (; e + 15 < e1; e += 16) {
                int s0 = srcs[e],      s1 = srcs[e + 1],  s2 = srcs[e + 2],  s3 = srcs[e + 3];
                int s4 = srcs[e + 4],  s5 = srcs[e + 5],  s6 = srcs[e + 6],  s7 = srcs[e + 7];
                int s8 = srcs[e + 8],  s9 = srcs[e + 9],  sa = srcs[e + 10], sb = srcs[e + 11];
                int sc = srcs[e + 12], sd = srcs[e + 13], se = srcs[e + 14], sf = srcs[e + 15];
                float d0 = dinv[s0], d1 = dinv[s1], d2 = dinv[s2], d3 = dinv[s3];
                float d4 = dinv[s4], d5 = dinv[s5], d6 = dinv[s6], d7 = dinv[s7];
                float d8 = dinv[s8], d9 = dinv[s9], da = dinv[sa], db = dinv[sb];
                float dc = dinv[sc], dd = dinv[sd], de = dinv[se], df = dinv[sf];
                uint4 u0 = hs4[(size_t)s0 * 16 + sub];
                uint4 u1 = hs4[(size_t)s1 * 16 + sub];
                uint4 u2 = hs4[(size_t)s2 * 16 + sub];
                uint4 u3 = hs4[(size_t)s3 * 16 + sub];
                uint4 u4 = hs4[(size_t)s4 * 16 + sub];
                uint4 u5 = hs4[(size_t)s5 * 16 + sub];
                uint4 u6 = hs4[(size_t)s6 * 16 + sub];
                uint4 u7 = hs4[(size_t)s7 * 16 + sub];
                uint4 u8 = hs4[(size_t)s8 * 16 + sub];
                uint4 u9 = hs4[(size_t)s9 * 16 + sub];
                uint4 ua = hs4[(size_t)sa * 16 + sub];
                uint4 ub = hs4[(size_t)sb * 16 + sub];
                uint4 uc = hs4[(size_t)sc * 16 + sub];
                uint4 ud = hs4[(size_t)sd * 16 + sub];
                uint4 ue = hs4[(size_t)se * 16 + sub];
                uint4 uf = hs4[(size_t)sf * 16 + sub];
                ACCS(u0, d0) ACCS(u1, d1) ACCS(u2, d2) ACCS(u3, d3)
                ACCS(u4, d4) ACCS(u5, d5) ACCS(u6, d6) ACCS(u7, d7)
                ACCS(u8, d8) ACCS(u9, d9) ACCS(ua, da) ACCS(ub, db)
                ACCS(uc, dc) ACCS(ud, dd) ACCS(ue, de) ACCS(uf, df)
            }
            for (; e + 7 < e1; e += 8) {
                int s0 = srcs[e],     s1 = srcs[e + 1], s2 = srcs[e + 2], s3 = srcs[e + 3];
                int s4 = srcs[e + 4], s5 = srcs[e + 5], s6 = srcs[e + 6], s7 = srcs[e + 7];
                float d0 = dinv[s0], d1 = dinv[s1], d2 = dinv[s2], d3 = dinv[s3];
                float d4 = dinv[s4], d5 = dinv[s5], d6 = dinv[s6], d7 = dinv[s7];
                uint4 u0 = hs4[(size_t)s0 * 16 + sub];
                uint4 u1 = hs4[(size_t)s1 * 16 + sub];
                uint4 u2 = hs4[(size_t)s2 * 16 + sub];
                uint4 u3 = hs4[(size_t)s3 * 16 + sub];
                uint4 u4 = hs4[(size_t)s4 * 16 + sub];
                uint4 u5 = hs4[(size_t)s5 * 16 + sub];
                uint4 u6 = hs4[(size_t)s6 * 16 + sub];
                uint4 u7 = hs4[(size_t)s7 * 16 + sub];
                ACCS(u0, d0) ACCS(u1, d1) ACCS(u2, d2) ACCS(u3, d3)
                ACCS(u4, d4) ACCS(u5, d5) ACCS(u6, d6) ACCS(u7, d7)
            }
            for (; e + 3 < e1; e += 4) {
                int s0 = srcs[e], s1 = srcs[e + 1], s2 = srcs[e + 2], s3 = srcs[e + 3];
                float d0 = dinv[s0], d1 = dinv[s1], d2 = dinv[s2], d3 = dinv[s3];
                uint4 u0 = hs4[(size_t)s0 * 16 + sub];
                uint4 u1 = hs4[(size_t)s1 * 16 + sub];
                uint4 u2 = hs4[(size_t)s2 * 16 + sub];
                uint4 u3 = hs4[(size_t)s3 * 16 + sub];
                ACCS(u0, d0) ACCS(u1, d1) ACCS(u2, d2) ACCS(u3, d3)
            }
            for (; e < e1; ++e) {
                int s0 = srcs[e];
                float d0 = dinv[s0];
                uint4 u0 = hs4[(size_t)s0 * 16 + sub];
                ACCS(u0, d0)
            }
            racc[0] += fmaxf(fmaf(a0, di, bb0.x), 0.f);
            racc[1] += fmaxf(fmaf(a1, di, bb0.y), 0.f);
            racc[2] += fmaxf(fmaf(a2, di, bb0.z), 0.f);
            racc[3] += fmaxf(fmaf(a3, di, bb0.w), 0.f);
            racc[4] += fmaxf(fmaf(a4, di, bb1.x), 0.f);
            racc[5] += fmaxf(fmaf(a5, di, bb1.y), 0.f);
            racc[6] += fmaxf(fmaf(a6, di, bb1.z), 0.f);
            racc[7] += fmaxf(fmaf(a7, di, bb1.w), 0.f);
        }
    }
    if (cur_lg >= 0) {
        float* gp = lds_pool ? &gacc[cur_lg * 128 + sub * 8]
                             : &gsum[(g_first + cur_lg) * 128 + sub * 8];
#pragma unroll
        for (int j = 0; j < 8; j++) atomicAdd(&gp[j], racc[j]);
    }
    __syncthreads();
    for (int idx = tid; idx < slots * 128; idx += 256) {
        float v = gacc[idx];
        if (v != 0.f)
            atomicAdd(&gsum[(g_first + (idx >> 7)) * 128 + (idx & 127)], v);
    }
}

// ---------------- K7: head (mean, fc1 + relu, actor softmax, critic) -------
__global__ __launch_bounds__(64) void k_head(const float* __restrict__ gsum,
                                             const int* __restrict__ batch,
                                             const float* __restrict__ fc1_w,
                                             const float* __restrict__ fc1_b,
                                             const float* __restrict__ actor_w,
                                             const float* __restrict__ actor_b,
                                             const float* __restrict__ critic_w,
                                             const float* __restrict__ critic_b,
                                             float* __restrict__ out) {
    __shared__ float gs[128];
    __shared__ float zs[64];
    __shared__ float ls[8], es[8];
    int g = blockIdx.x, t = threadIdx.x;
    int lo = lbound(batch, NN, g), hi = lbound(batch, NN, g + 1);
    float invc = 1.f / fmaxf((float)(hi - lo), 1.f);
    gs[t] = gsum[g * 128 + t] * invc;
    gs[t + 64] = gsum[g * 128 + 64 + t] * invc;
    __syncthreads();
    float z = fc1_b[t];
    for (int k = 0; k < 128; k++) z = fmaf(gs[k], fc1_w[k * 64 + t], z);
    zs[t] = fmaxf(z, 0.f);
    __syncthreads();
    if (t < 8) {
        float l = actor_b[t];
        for (int k = 0; k < 64; k++) l = fmaf(zs[k], actor_w[k * 8 + t], l);
        ls[t] = l;
    }
    __syncthreads();
    if (t < 8) {
        float m = ls[0];
#pragma unroll
        for (int j = 1; j < 8; j++) m = fmaxf(m, ls[j]);
        es[t] = expf(ls[t] - m);
    }
    __syncthreads();
    if (t < 8) {
        float ssum = 0.f;
#pragma unroll
        for (int j = 0; j < 8; j++) ssum += es[j];
        out[g * 8 + t] = es[t] / ssum;
    }
    if (t == 32) {
        float v = critic_b[0];
        for (int k = 0; k < 64; k++) v = fmaf(zs[k], critic_w[k], v);
        out[GG * TT + g] = v;
    }
}

extern "C" void kernel_launch(void* const* d_in, const int* in_sizes, int n_in,
                              void* d_out, int out_size, void* d_ws, size_t ws_size,
                              hipStream_t stream) {
    const float* x        = (const float*)d_in[0];
    const int*   ei       = (const int*)d_in[1];
    const int*   batch    = (const int*)d_in[2];
    const float* W        = (const float*)d_in[3];
    const float* b        = (const float*)d_in[4];
    const float* fc1_w    = (const float*)d_in[5];
    const float* fc1_b    = (const float*)d_in[6];
    const float* actor_w  = (const float*)d_in[7];
    const float* actor_b  = (const float*)d_in[8];
    const float* critic_w = (const float*)d_in[9];
    const float* critic_b = (const float*)d_in[10];
    float* out = (float*)d_out;

    char* ws = (char*)d_ws;
    size_t off = 0;
    unsigned short* hs    = (unsigned short*)(ws + off); off += (size_t)NN * 128 * 2 + 64;  // 12.8 MB
    unsigned short* wt_bf = (unsigned short*)(ws + off); off += (size_t)128 * 128 * 2;      // 32 KB
    float* dinv      = (float*)(ws + off);    off += (size_t)NN * 4;
    int*   row_ptr   = (int*)(ws + off);      off += (size_t)(NN + 1) * 4 + 12;
    int*   srcs      = (int*)(ws + off);      off += (size_t)EE * 4;       // 3.2 MB
    unsigned* etmp   = (unsigned*)(ws + off); off += (size_t)EE * 4;       // 3.2 MB
    int*   table     = (int*)(ws + off);      off += (size_t)NSB * NB * 4; // 200 KB
    int*   bbase     = (int*)(ws + off);      off += (size_t)(NB + 1) * 4 + 12;
    float* gsum      = (float*)(ws + off);    off += (size_t)GG * HH * 4;

    const int* src = ei;        // edge_index[0]
    const int* dst = ei + EE;   // edge_index[1]

    k_front<<<NSB, 256, 0, stream>>>(dst, W, table, wt_bf, gsum);
    k_sg<<<NSB + GEMMB, 256, 0, stream>>>(src, dst, table, bbase, etmp,
                                          x, wt_bf, hs);
    k_csr<<<NB, 256, 0, stream>>>(etmp, bbase, row_ptr, dinv, srcs);
    k_aggr<<<(NN + 31) / 32, 256, 0, stream>>>((const uint4*)hs, row_ptr, srcs,
                                               dinv, b, batch, gsum);
    k_head<<<GG, 64, 0, stream>>>(gsum, batch, fc1_w, fc1_b, actor_w, actor_b,
                                  critic_w, critic_b, out);
}

// Round 9
// 184.423 us; speedup vs baseline: 1.0252x; 1.0252x over previous
//
#include <hip/hip_runtime.h>
#include <hip/hip_bf16.h>

#define NN 50000
#define EE 800000
#define FF 128
#define HH 128
#define HID2 64
#define TT 8
#define GG 64
#define NB 196          // buckets of 256 dst nodes (NN < 196*256; NN < 2^16)
#define NSB 256         // scatter blocks
#define EPB (EE / NSB)  // 3125 edges per scatter block
#define NPAD 50048      // NN padded to 64 (782 * 64)
#define GEMMB (NPAD / 64)  // 782 gemm tiles

using frag_ab = __attribute__((ext_vector_type(8))) short;  // 8 bf16
using frag_cd = __attribute__((ext_vector_type(4))) float;  // 4 fp32

__device__ inline unsigned short f2bf(float f) {
    union { float f; unsigned u; } v; v.f = f;
    unsigned r = v.u + 0x7fff + ((v.u >> 16) & 1);  // RNE
    return (unsigned short)(r >> 16);
}

__device__ inline int lbound(const int* __restrict__ a, int n, int key) {
    int lo = 0, hi = n;
    while (lo < hi) {
        int mid = (lo + hi) >> 1;
        if (a[mid] < key) lo = mid + 1;
        else hi = mid;
    }
    return lo;
}

// ---- K_FRONT: per-block bucket histogram + W->Wt bf16 + gsum zero ---------
__global__ __launch_bounds__(256) void k_front(const int* __restrict__ dst,
                                               const float* __restrict__ W,
                                               int* __restrict__ table,
                                               unsigned short* __restrict__ wt_bf,
                                               float* __restrict__ gsum) {
    __shared__ int cnt[NB];
    int t = threadIdx.x, blk = blockIdx.x;
    if (blk < 64) {
        int gid = blk * 256 + t;          // 16384 total
        int c = gid >> 7, k = gid & 127;
        wt_bf[gid] = f2bf(W[k * 128 + c]);
    }
    if (blk >= 64 && blk < 96) {
        int gid = (blk - 64) * 256 + t;   // 8192 floats
        gsum[gid] = 0.f;
    }
    for (int i = t; i < NB; i += 256) cnt[i] = 0;
    __syncthreads();
    int e0 = blk * EPB;
    for (int e = e0 + t; e < e0 + EPB; e += 256)
        atomicAdd(&cnt[dst[e] >> 8], 1);
    __syncthreads();
    for (int i = t; i < NB; i += 256) table[blk * NB + i] = cnt[i];
}

// ---- K_SG: co-launched [sort: blocks 0..255] ∥ [gemm: blocks 256..1037] ---
__global__ __launch_bounds__(256) void k_sg(const int* __restrict__ src,
                                            const int* __restrict__ dst,
                                            const int* __restrict__ table,
                                            int* __restrict__ bbase,
                                            unsigned* __restrict__ etmp,
                                            const float* __restrict__ x,
                                            const unsigned short* __restrict__ wt_bf,
                                            unsigned short* __restrict__ hs) {
    int t = threadIdx.x, blk = blockIdx.x;
    if (blk < NSB) {
        __shared__ int s[256];
        __shared__ int ofs[NB];
        __shared__ int cur[NB];
        int pr = 0, to = 0;
        if (t < NB) {
#pragma unroll 8
            for (int r = 0; r < 256; r++) {
                int v = table[r * NB + t];
                to += v;
                pr += (r < blk) ? v : 0;
            }
        }
        s[t] = (t < NB) ? to : 0;
        __syncthreads();
        for (int off = 1; off < 256; off <<= 1) {
            int a = s[t];
            int w = (t >= off) ? s[t - off] : 0;
            __syncthreads();
            s[t] = a + w;
            __syncthreads();
        }
        if (t < NB) {
            int bb = s[t] - to;            // exclusive bucket base
            ofs[t] = pr + bb;
            cur[t] = 0;
            if (blk == 0) bbase[t] = bb;
        }
        if (blk == 0 && t == 0) bbase[NB] = EE;
        __syncthreads();
        int e0 = blk * EPB;
        for (int e = e0 + t; e < e0 + EPB; e += 256) {
            int d = dst[e];
            int b = d >> 8;
            int r = atomicAdd(&cur[b], 1);
            etmp[ofs[b] + r] = ((unsigned)d << 16) | (unsigned)src[e];
        }
    } else {
        // ---- gemm tile (raw bf16 output; dinv applied in aggr) ----
        int vb = blk - NSB;               // 0..781
        int w = t >> 6, lane = t & 63;
        int m = lane & 15, quad = lane >> 4;
        int r0 = vb * 64 + w * 16;
        int row = r0 + m;
        frag_cd acc[8];
#pragma unroll
        for (int nt = 0; nt < 8; nt++) acc[nt] = frag_cd{0.f, 0.f, 0.f, 0.f};
#pragma unroll
        for (int k0 = 0; k0 < 128; k0 += 32) {
            unsigned short av[8];
            if (row < NN) {
                const float4* pp = (const float4*)(x + (size_t)row * 128 + k0 + quad * 8);
                float4 a0 = pp[0], a1 = pp[1];
                av[0] = f2bf(a0.x); av[1] = f2bf(a0.y); av[2] = f2bf(a0.z); av[3] = f2bf(a0.w);
                av[4] = f2bf(a1.x); av[5] = f2bf(a1.y); av[6] = f2bf(a1.z); av[7] = f2bf(a1.w);
            } else {
#pragma unroll
                for (int j = 0; j < 8; j++) av[j] = 0;
            }
            frag_ab a = *(const frag_ab*)av;
#pragma unroll
            for (int nt = 0; nt < 8; nt++) {
                frag_ab bfr = *(const frag_ab*)(wt_bf + (size_t)(nt * 16 + m) * 128 + k0 + quad * 8);
                acc[nt] = __builtin_amdgcn_mfma_f32_16x16x32_bf16(a, bfr, acc[nt], 0, 0, 0);
            }
        }
#pragma unroll
        for (int reg = 0; reg < 4; reg++) {
            int gr = r0 + quad * 4 + reg;
            if (gr < NN) {
#pragma unroll
                for (int nt = 0; nt < 8; nt++)
                    hs[(size_t)gr * 128 + nt * 16 + m] = f2bf(acc[nt][reg]);
            }
        }
    }
}

// ---- K_CSR: per-bucket  hist -> scan -> row_ptr/dinv -> CSR fill ----------
__global__ __launch_bounds__(256) void k_csr(const unsigned* __restrict__ etmp,
                                             const int* __restrict__ bbase,
                                             int* __restrict__ row_ptr,
                                             float* __restrict__ dinv,
                                             int* __restrict__ srcs) {
    __shared__ int s[256];
    __shared__ int cur[256];
    int t = threadIdx.x, b = blockIdx.x;
    s[t] = 0;
    __syncthreads();
    int e0 = bbase[b], e1 = bbase[b + 1];
    for (int e = e0 + t; e < e1; e += 256)
        atomicAdd(&s[(etmp[e] >> 16) & 255], 1);
    __syncthreads();
    int v = s[t];
    for (int off = 1; off < 256; off <<= 1) {
        int a = s[t];
        int w = (t >= off) ? s[t - off] : 0;
        __syncthreads();
        s[t] = a + w;
        __syncthreads();
    }
    int excl = s[t] - v + e0;   // e0 == bbase[b] == row_ptr[b*256]
    int node = b * 256 + t;
    if (node < NN) {
        row_ptr[node] = excl;
        dinv[node] = rsqrtf((float)(v + 1));  // +1 self-loop
    }
    if (b == NB - 1 && t == 0) row_ptr[NN] = EE;
    cur[t] = excl;
    __syncthreads();
    for (int e = e0 + t; e < e1; e += 256) {
        unsigned u = etmp[e];
        int slot = atomicAdd(&cur[(u >> 16) & 255], 1);
        srcs[slot] = (int)(u & 0xffffu);
    }
}

// ---------------- K5: gather(+dinv[src] fma) + bias + relu + pool ----------
// r7-proven per-qwave body (8-deep ACCS pipeline, per-node prologue) in
// 128-thread / 2-wave / 16-node blocks: same total waves (6250), but 2x the
// schedulable block units -> better sustained residency + smaller tail.
// Flush atomics ~2x (priced ~+2us from r3 data); occupancy is the bet.
#define ACCS(u, ds) \
    a0 = fmaf(ds, __uint_as_float((u).x << 16), a0); \
    a1 = fmaf(ds, __uint_as_float((u).x & 0xffff0000u), a1); \
    a2 = fmaf(ds, __uint_as_float((u).y << 16), a2); \
    a3 = fmaf(ds, __uint_as_float((u).y & 0xffff0000u), a3); \
    a4 = fmaf(ds, __uint_as_float((u).z << 16), a4); \
    a5 = fmaf(ds, __uint_as_float((u).z & 0xffff0000u), a5); \
    a6 = fmaf(ds, __uint_as_float((u).w << 16), a6); \
    a7 = fmaf(ds, __uint_as_float((u).w & 0xffff0000u), a7);

__global__ __launch_bounds__(128) void k_aggr(const uint4* __restrict__ hs4,
                                              const int* __restrict__ row_ptr,
                                              const int* __restrict__ srcs,
                                              const float* __restrict__ dinv,
                                              const float* __restrict__ bias,
                                              const int* __restrict__ batch,
                                              float* __restrict__ gsum) {
    __shared__ float gacc[8 * 128];   // 4 KB: 8 group slots (span>8 -> global)
    int tid = threadIdx.x;
    int qid = tid >> 4, sub = tid & 15;   // qid 0..7
    int i_base = blockIdx.x * 16;         // 3125 blocks * 16 = NN exactly
    int g_first = batch[i_base];
    int last = i_base + 15; if (last >= NN) last = NN - 1;
    int gspan = batch[last] - g_first + 1;
    bool lds_pool = (gspan <= 8);
    int slots = lds_pool ? gspan : 0;
    for (int idx = tid; idx < slots * 128; idx += 128) gacc[idx] = 0.f;
    __syncthreads();

    const float4* b4 = (const float4*)(bias + sub * 8);
    float4 bb0 = b4[0], bb1 = b4[1];

    float racc[8];
#pragma unroll
    for (int j = 0; j < 8; j++) racc[j] = 0.f;
    int cur_lg = -1;

    for (int n = 0; n < 2; n++) {
        int i = i_base + qid * 2 + n;
        if (i >= NN) break;
        int lg = batch[i] - g_first;
        if (lg != cur_lg) {
            if (cur_lg >= 0) {
                float* gp = lds_pool ? &gacc[cur_lg * 128 + sub * 8]
                                     : &gsum[(g_first + cur_lg) * 128 + sub * 8];
#pragma unroll
                for (int j = 0; j < 8; j++) atomicAdd(&gp[j], racc[j]);
#pragma unroll
                for (int j = 0; j < 8; j++) racc[j] = 0.f;
            }
            cur_lg = lg;
        }
        float di = dinv[i];
        uint4 su = hs4[(size_t)i * 16 + sub];
        // self term: dinv[i] * h_raw[i]
        float a0 = di * __uint_as_float(su.x << 16);
        float a1 = di * __uint_as_float(su.x & 0xffff0000u);
        float a2 = di * __uint_as_float(su.y << 16);
        float a3 = di * __uint_as_float(su.y & 0xffff0000u);
        float a4 = di * __uint_as_float(su.z << 16);
        float a5 = di * __uint_as_float(su.z & 0xffff0000u);
        float a6 = di * __uint_as_float(su.w << 16);
        float a7 = di * __uint_as_float(su.w & 0xffff0000u);
        int e = row_ptr[i], e1 = row_ptr[i + 1];
        for (; e + 7 < e1; e += 8) {
            int s0 = srcs[e],     s1 = srcs[e + 1], s2 = srcs[e + 2], s3 = srcs[e + 3];
            int s4 = srcs[e + 4], s5 = srcs[e + 5], s6 = srcs[e + 6], s7 = srcs[e + 7];
            float d0 = dinv[s0], d1 = dinv[s1], d2 = dinv[s2], d3 = dinv[s3];
            float d4 = dinv[s4], d5 = dinv[s5], d6 = dinv[s6], d7 = dinv[s7];
            uint4 u0 = hs4[(size_t)s0 * 16 + sub];
            uint4 u1 = hs4[(size_t)s1 * 16 + sub];
            uint4 u2 = hs4[(size_t)s2 * 16 + sub];
            uint4 u3 = hs4[(size_t)s3 * 16 + sub];
            uint4 u4 = hs4[(size_t)s4 * 16 + sub];
            uint4 u5 = hs4[(size_t)s5 * 16 + sub];
            uint4 u6 = hs4[(size_t)s6 * 16 + sub];
            uint4 u7 = hs4[(size_t)s7 * 16 + sub];
            ACCS(u0, d0) ACCS(u1, d1) ACCS(u2, d2) ACCS(u3, d3)
            ACCS(u4, d4) ACCS(u5, d5) ACCS(u6, d6) ACCS(u7, d7)
        }
        for (; e + 3 < e1; e += 4) {
            int s0 = srcs[e], s1 = srcs[e + 1], s2 = srcs[e + 2], s3 = srcs[e + 3];
            float d0 = dinv[s0], d1 = dinv[s1], d2 = dinv[s2], d3 = dinv[s3];
            uint4 u0 = hs4[(size_t)s0 * 16 + sub];
            uint4 u1 = hs4[(size_t)s1 * 16 + sub];
            uint4 u2 = hs4[(size_t)s2 * 16 + sub];
            uint4 u3 = hs4[(size_t)s3 * 16 + sub];
            ACCS(u0, d0) ACCS(u1, d1) ACCS(u2, d2) ACCS(u3, d3)
        }
        for (; e < e1; ++e) {
            int s0 = srcs[e];
            float d0 = dinv[s0];
            uint4 u0 = hs4[(size_t)s0 * 16 + sub];
            ACCS(u0, d0)
        }
        racc[0] += fmaxf(fmaf(a0, di, bb0.x), 0.f);
        racc[1] += fmaxf(fmaf(a1, di, bb0.y), 0.f);
        racc[2] += fmaxf(fmaf(a2, di, bb0.z), 0.f);
        racc[3] += fmaxf(fmaf(a3, di, bb0.w), 0.f);
        racc[4] += fmaxf(fmaf(a4, di, bb1.x), 0.f);
        racc[5] += fmaxf(fmaf(a5, di, bb1.y), 0.f);
        racc[6] += fmaxf(fmaf(a6, di, bb1.z), 0.f);
        racc[7] += fmaxf(fmaf(a7, di, bb1.w), 0.f);
    }
    if (cur_lg >= 0) {
        float* gp = lds_pool ? &gacc[cur_lg * 128 + sub * 8]
                             : &gsum[(g_first + cur_lg) * 128 + sub * 8];
#pragma unroll
        for (int j = 0; j < 8; j++) atomicAdd(&gp[j], racc[j]);
    }
    __syncthreads();
    for (int idx = tid; idx < slots * 128; idx += 128) {
        float v = gacc[idx];
        if (v != 0.f)
            atomicAdd(&gsum[(g_first + (idx >> 7)) * 128 + (idx & 127)], v);
    }
}

// ---------------- K7: head (mean, fc1 + relu, actor softmax, critic) -------
__global__ __launch_bounds__(64) void k_head(const float* __restrict__ gsum,
                                             const int* __restrict__ batch,
                                             const float* __restrict__ fc1_w,
                                             const float* __restrict__ fc1_b,
                                             const float* __restrict__ actor_w,
                                             const float* __restrict__ actor_b,
                                             const float* __restrict__ critic_w,
                                             const float* __restrict__ critic_b,
                                             float* __restrict__ out) {
    __shared__ float gs[128];
    __shared__ float zs[64];
    __shared__ float ls[8], es[8];
    int g = blockIdx.x, t = threadIdx.x;
    int lo = lbound(batch, NN, g), hi = lbound(batch, NN, g + 1);
    float invc = 1.f / fmaxf((float)(hi - lo), 1.f);
    gs[t] = gsum[g * 128 + t] * invc;
    gs[t + 64] = gsum[g * 128 + 64 + t] * invc;
    __syncthreads();
    float z = fc1_b[t];
    for (int k = 0; k < 128; k++) z = fmaf(gs[k], fc1_w[k * 64 + t], z);
    zs[t] = fmaxf(z, 0.f);
    __syncthreads();
    if (t < 8) {
        float l = actor_b[t];
        for (int k = 0; k < 64; k++) l = fmaf(zs[k], actor_w[k * 8 + t], l);
        ls[t] = l;
    }
    __syncthreads();
    if (t < 8) {
        float m = ls[0];
#pragma unroll
        for (int j = 1; j < 8; j++) m = fmaxf(m, ls[j]);
        es[t] = expf(ls[t] - m);
    }
    __syncthreads();
    if (t < 8) {
        float ssum = 0.f;
#pragma unroll
        for (int j = 0; j < 8; j++) ssum += es[j];
        out[g * 8 + t] = es[t] / ssum;
    }
    if (t == 32) {
        float v = critic_b[0];
        for (int k = 0; k < 64; k++) v = fmaf(zs[k], critic_w[k], v);
        out[GG * TT + g] = v;
    }
}

extern "C" void kernel_launch(void* const* d_in, const int* in_sizes, int n_in,
                              void* d_out, int out_size, void* d_ws, size_t ws_size,
                              hipStream_t stream) {
    const float* x        = (const float*)d_in[0];
    const int*   ei       = (const int*)d_in[1];
    const int*   batch    = (const int*)d_in[2];
    const float* W        = (const float*)d_in[3];
    const float* b        = (const float*)d_in[4];
    const float* fc1_w    = (const float*)d_in[5];
    const float* fc1_b    = (const float*)d_in[6];
    const float* actor_w  = (const float*)d_in[7];
    const float* actor_b  = (const float*)d_in[8];
    const float* critic_w = (const float*)d_in[9];
    const float* critic_b = (const float*)d_in[10];
    float* out = (float*)d_out;

    char* ws = (char*)d_ws;
    size_t off = 0;
    unsigned short* hs    = (unsigned short*)(ws + off); off += (size_t)NN * 128 * 2 + 64;  // 12.8 MB
    unsigned short* wt_bf = (unsigned short*)(ws + off); off += (size_t)128 * 128 * 2;      // 32 KB
    float* dinv      = (float*)(ws + off);    off += (size_t)NN * 4;
    int*   row_ptr   = (int*)(ws + off);      off += (size_t)(NN + 1) * 4 + 12;
    int*   srcs      = (int*)(ws + off);      off += (size_t)EE * 4;       // 3.2 MB
    unsigned* etmp   = (unsigned*)(ws + off); off += (size_t)EE * 4;       // 3.2 MB
    int*   table     = (int*)(ws + off);      off += (size_t)NSB * NB * 4; // 200 KB
    int*   bbase     = (int*)(ws + off);      off += (size_t)(NB + 1) * 4 + 12;
    float* gsum      = (float*)(ws + off);    off += (size_t)GG * HH * 4;

    const int* src = ei;        // edge_index[0]
    const int* dst = ei + EE;   // edge_index[1]

    k_front<<<NSB, 256, 0, stream>>>(dst, W, table, wt_bf, gsum);
    k_sg<<<NSB + GEMMB, 256, 0, stream>>>(src, dst, table, bbase, etmp,
                                          x, wt_bf, hs);
    k_csr<<<NB, 256, 0, stream>>>(etmp, bbase, row_ptr, dinv, srcs);
    k_aggr<<<NN / 16, 128, 0, stream>>>((const uint4*)hs, row_ptr, srcs,
                                        dinv, b, batch, gsum);
    k_head<<<GG, 64, 0, stream>>>(gsum, batch, fc1_w, fc1_b, actor_w, actor_b,
                                  critic_w, critic_b, out);
}